// Round 1
// 225.695 us; speedup vs baseline: 1.0207x; 1.0207x over previous
//
#include <hip/hip_runtime.h>
#include <hip/hip_bf16.h>

// Linear1d: out[B,256] = (x[B,512] @ W[256,512]^T) / 8 + 0.1*bias
// R5: kill the 16-way LDS bank conflict (SQ_LDS_BANK_CONFLICT 2.94e7 ->
// ~57% of gemm cycles). Reads at l16*2048 + q*32 + kc*128 put all 16 l16
// lanes on one bank quad. Fix per rule #21 (global_load_lds writes linearly):
// XOR-swizzle phys = logical ^ ((row&7)<<4), applied as inverse-swizzled
// per-lane GLOBAL source at stage time (srclane = lane ^ (row&7); row is
// wave-uniform) + the same XOR on the read-side LDS byte offset. Everything
// else (DMA staging, stationary W in 128 regs, late stores) unchanged.

typedef __bf16 bf16;
typedef __attribute__((ext_vector_type(8))) __bf16 bf16x8;
typedef __attribute__((ext_vector_type(4))) __bf16 bf16x4;
typedef __attribute__((ext_vector_type(4))) float f32x4;

#define BATCH_ 65536
#define KDIM   512
#define NDIM   256
#define CHUNK_ROWS 16
#define CHUNKS 16                  // per block
#define ROWS_PER_BLOCK (CHUNK_ROWS * CHUNKS)   // 256
#define CHUNK_BYTES (CHUNK_ROWS * KDIM * 4)    // 32 KB

__global__ __launch_bounds__(256) void wcvt_kernel(const float* __restrict__ w,
                                                   bf16* __restrict__ wb) {
    int i = (blockIdx.x * 256 + threadIdx.x) * 4;
    f32x4 v = *(const f32x4*)(w + i);
    bf16x4 o;
    o[0] = (bf16)(v.x * 0.125f);
    o[1] = (bf16)(v.y * 0.125f);
    o[2] = (bf16)(v.z * 0.125f);
    o[3] = (bf16)(v.w * 0.125f);
    *(bf16x4*)(wb + i) = o;
}

__device__ __forceinline__ void stage_chunk(const float* xc, float* buf, int tid) {
    // 32 KB chunk: 4 passes x (512 thr x 16 B). LDS dest stays LINEAR
    // (wave-uniform base + lane*16, as the DMA requires). The bank-swizzle
    // is realized by permuting the per-lane GLOBAL source: each wave covers
    // one half-row (row = 4p + (w>>1), wave-uniform), and within the row the
    // swizzle phys^=((row&7)<<4) is just lane ^= (row&7).
    const int lane = tid & 63;
    const int w    = tid >> 6;
#pragma unroll
    for (int p = 0; p < 4; ++p) {
        const int row = p * 4 + (w >> 1);          // wave-uniform chunk row
        const int sl  = lane ^ (row & 7);          // inverse-swizzled src lane
        const char* g = (const char*)xc + p * 8192 + w * 1024 + sl * 16;
        char* l = (char*)buf + p * 8192 + w * 1024;
        __builtin_amdgcn_global_load_lds(
            (const __attribute__((address_space(1))) void*)g,
            (__attribute__((address_space(3))) void*)l, 16, 0, 0);
    }
}

__device__ __forceinline__ bf16x8 cvt_a(f32x4 lo, f32x4 hi) {
    bf16x8 a;
    a[0] = (bf16)lo.x; a[1] = (bf16)lo.y; a[2] = (bf16)lo.z; a[3] = (bf16)lo.w;
    a[4] = (bf16)hi.x; a[5] = (bf16)hi.y; a[6] = (bf16)hi.z; a[7] = (bf16)hi.w;
    return a;
}

__device__ __forceinline__ void compute_chunk(const float* buf,
                                              const bf16x8 (&wf)[16][2],
                                              int l16, int q, f32x4 (&acc)[2]) {
    acc[0] = (f32x4)0.0f;
    acc[1] = (f32x4)0.0f;
    // Swizzled read: logical byte L = l16*2048 + q*32 + kc*128 + h*16,
    // physical = L ^ ((l16&7)<<4). kc*128 and l16*2048 don't touch bits 4-6,
    // so the XOR folds into the (q*32 + h*16) field. Lanes l16=0..7 now hit
    // 8 distinct bank quads (2-way alias with l16+8 is free).
    const char* base = (const char*)buf + l16 * 2048;
    const int xo     = (l16 & 7) << 4;
    const int off_lo = (q * 32) ^ xo;
    const int off_hi = (q * 32 + 16) ^ xo;
#pragma unroll
    for (int kc = 0; kc < 16; ++kc) {
        f32x4 lo = *(const f32x4*)(base + kc * 128 + off_lo);
        f32x4 hi = *(const f32x4*)(base + kc * 128 + off_hi);
        bf16x8 a = cvt_a(lo, hi);
        acc[0] = __builtin_amdgcn_mfma_f32_16x16x32_bf16(a, wf[kc][0], acc[0], 0, 0, 0);
        acc[1] = __builtin_amdgcn_mfma_f32_16x16x32_bf16(a, wf[kc][1], acc[1], 0, 0, 0);
    }
}

__global__ __launch_bounds__(512, 2) void gemm_kernel(const float* __restrict__ x,
                                                      const bf16* __restrict__ wb,
                                                      const float* __restrict__ bias,
                                                      float* __restrict__ out) {
    __shared__ __align__(16) float bufA[CHUNK_ROWS * KDIM];  // 32 KB
    __shared__ __align__(16) float bufB[CHUNK_ROWS * KDIM];  // 32 KB

    const int tid  = threadIdx.x;
    const int lane = tid & 63;
    const int w    = tid >> 6;     // wave 0..7 -> 32 N-columns each
    const int q    = lane >> 4;
    const int l16  = lane & 15;
    const int n0   = w * 32;
    const long row_base = (long)blockIdx.x * ROWS_PER_BLOCK;

    // Stationary W: wf[kc][nt] = W[n0+nt*16+l16][kc*32+q*8 .. +7]  (128 regs)
    bf16x8 wf[16][2];
#pragma unroll
    for (int kc = 0; kc < 16; ++kc)
#pragma unroll
        for (int nt = 0; nt < 2; ++nt)
            wf[kc][nt] = *(const bf16x8*)(wb + (long)(n0 + nt * 16 + l16) * KDIM
                                             + kc * 32 + q * 8);
    float bv[2];
    bv[0] = 0.1f * bias[n0 + l16];
    bv[1] = 0.1f * bias[n0 + 16 + l16];

    const float* xblk = x + row_base * KDIM;

    // Prologue: chunk 0 -> bufA.
    stage_chunk(xblk, bufA, tid);
    __syncthreads();

    f32x4 acc[2];
#pragma unroll 1
    for (int t = 0; t < CHUNKS; t += 2) {
        // ---- even chunk t: compute bufA, prefetch t+1 -> bufB ----
        if (t + 1 < CHUNKS)
            stage_chunk(xblk + (long)(t + 1) * CHUNK_ROWS * KDIM, bufB, tid);
        compute_chunk(bufA, wf, l16, q, acc);
        __syncthreads();   // drains loads(t+1) after a full compute phase
        {
            const long row0 = row_base + (long)t * CHUNK_ROWS;
#pragma unroll
            for (int nt = 0; nt < 2; ++nt)
#pragma unroll
                for (int r = 0; r < 4; ++r)
                    out[(row0 + q * 4 + r) * NDIM + n0 + nt * 16 + l16] = acc[nt][r] + bv[nt];
        }

        // ---- odd chunk t+1: compute bufB, prefetch t+2 -> bufA ----
        if (t + 2 < CHUNKS)
            stage_chunk(xblk + (long)(t + 2) * CHUNK_ROWS * KDIM, bufA, tid);
        compute_chunk(bufB, wf, l16, q, acc);
        __syncthreads();
        {
            const long row0 = row_base + (long)(t + 1) * CHUNK_ROWS;
#pragma unroll
            for (int nt = 0; nt < 2; ++nt)
#pragma unroll
                for (int r = 0; r < 4; ++r)
                    out[(row0 + q * 4 + r) * NDIM + n0 + nt * 16 + l16] = acc[nt][r] + bv[nt];
        }
    }
}

extern "C" void kernel_launch(void* const* d_in, const int* in_sizes, int n_in,
                              void* d_out, int out_size, void* d_ws, size_t ws_size,
                              hipStream_t stream) {
    const float* x    = (const float*)d_in[0];
    const float* w    = (const float*)d_in[1];
    const float* bias = (const float*)d_in[2];
    float* out = (float*)d_out;
    bf16* wb   = (bf16*)d_ws;   // 256*512*2 = 256 KB scratch

    wcvt_kernel<<<(NDIM * KDIM) / (256 * 4), 256, 0, stream>>>(w, wb);
    gemm_kernel<<<BATCH_ / ROWS_PER_BLOCK, 512, 0, stream>>>(x, wb, bias, out);
}